// Round 12
// baseline (190.912 us; speedup 1.0000x reference)
//
#include <hip/hip_runtime.h>
#include <cfloat>

#define SEQ   2048
#define NE    2048
#define NH    16
#define DIM   128
#define NKV   384
#define QSCALE 0.022097086912079611f  // 1/sqrt(2048)

typedef __attribute__((ext_vector_type(8))) short bf16x8;      // MFMA A/B frag (4 VGPR)
typedef __attribute__((ext_vector_type(4))) float f32x4;       // 16x16 C/D frag
typedef __attribute__((ext_vector_type(16))) float f32x16;     // 32x32 C/D frag
typedef __attribute__((ext_vector_type(8))) unsigned short u16x8;
typedef __attribute__((ext_vector_type(4))) unsigned int u32x4;
typedef __attribute__((ext_vector_type(2))) unsigned int u32x2;

#define PSLOT_B 33792u       // bytes/slot: f32 m[128], l[128], bf16 O[128][128]
#define NUNITS  384          // 16 heads x 24 units (QBLK=128, chunk = 16 KV-tiles)

__device__ __forceinline__ unsigned short f32_to_bf16_rn(float x) {
    unsigned u = __builtin_bit_cast(unsigned, x);
    u += 0x7fffu + ((u >> 16) & 1u);          // round-to-nearest-even
    return (unsigned short)(u >> 16);
}

__device__ __forceinline__ unsigned cvt_pk_bf16(float lo, float hi) {
    unsigned r;
    asm("v_cvt_pk_bf16_f32 %0, %1, %2" : "=v"(r) : "v"(lo), "v"(hi));
    return r;
}
__device__ __forceinline__ float bf16lo(unsigned w) {
    return __builtin_bit_cast(float, w << 16);
}
__device__ __forceinline__ float bf16hi(unsigned w) {
    return __builtin_bit_cast(float, w & 0xFFFF0000u);
}

__device__ __forceinline__ void gload16(const void* g, void* l) {
    __builtin_amdgcn_global_load_lds(
        (const __attribute__((address_space(1))) unsigned int*)g,
        (__attribute__((address_space(3))) unsigned int*)l, 16, 0, 0);
}

// ============ convert fp32 -> bf16 (elementwise) ============
__global__ __launch_bounds__(256) void convert_bf16_kernel(
    const float* __restrict__ src, unsigned short* __restrict__ dst, int n4)
{
    for (int i = blockIdx.x * 256 + threadIdx.x; i < n4; i += gridDim.x * 256) {
        float4 x = ((const float4*)src)[i];
        ushort4 h;
        h.x = f32_to_bf16_rn(x.x);
        h.y = f32_to_bf16_rn(x.y);
        h.z = f32_to_bf16_rn(x.z);
        h.w = f32_to_bf16_rn(x.w);
        ((ushort4*)dst)[i] = h;
    }
}

// ====== transpose-convert: src[b][K][N] fp32 -> dst[b][N][K] bf16 ======
__global__ __launch_bounds__(256) void transpose_bf16_kernel(
    const float* __restrict__ src, unsigned short* __restrict__ dst, int K, int N)
{
    const int kt = blockIdx.x, nt = blockIdx.y, b = blockIdx.z;
    const float* s = src + (size_t)b * K * N;
    __shared__ float tile[64][65];
    const int tid = threadIdx.x;
    #pragma unroll
    for (int i = 0; i < 4; i++) {
        int idx = tid + 256 * i;
        int kk = idx >> 4, n4 = idx & 15;
        float4 val = *(const float4*)&s[(size_t)(kt * 64 + kk) * N + nt * 64 + n4 * 4];
        tile[kk][n4 * 4 + 0] = val.x; tile[kk][n4 * 4 + 1] = val.y;
        tile[kk][n4 * 4 + 2] = val.z; tile[kk][n4 * 4 + 3] = val.w;
    }
    __syncthreads();
    #pragma unroll
    for (int i = 0; i < 2; i++) {
        int idx = tid + 256 * i;
        int nn = idx >> 3, k8 = idx & 7;
        u16x8 hv;
        #pragma unroll
        for (int j = 0; j < 8; j++)
            hv[j] = f32_to_bf16_rn(tile[k8 * 8 + j][nn]);
        size_t off = ((size_t)b * N + nt * 64 + nn) * K + kt * 64 + k8 * 8;
        *(u16x8*)&dst[off] = hv;
    }
}

// ============ bf16 MFMA GEMM, 128x128 (qkv projection) ============
__global__ __launch_bounds__(256, 4) void gemm_qkv_kernel(
    const unsigned short* __restrict__ A, const unsigned short* __restrict__ B,
    const float* __restrict__ bias,
    unsigned short* __restrict__ o0, unsigned short* __restrict__ o1,
    unsigned short* __restrict__ o2)
{
    __shared__ unsigned short smem[2][128][64];
    const int tid = threadIdx.x;
    const int wave = tid >> 6, lane = tid & 63;
    const int s0 = blockIdx.x * 128, n0 = blockIdx.y * 128, z = blockIdx.z;
    const int bRowBase = z * NKV + n0;

    const int srow = lane >> 3;
    const int sswz = ((lane & 7) ^ srow) << 4;
    size_t aoff[4], boff[4];
    #pragma unroll
    for (int j = 0; j < 4; j++) {
        int ra = s0 + wave * 32 + j * 8 + srow;
        int rb = bRowBase + wave * 32 + j * 8 + srow;
        aoff[j] = 2 * ((size_t)ra * NE) + sswz;
        boff[j] = 2 * ((size_t)rb * NE) + sswz;
    }
    const char* pA = (const char*)A;
    const char* pB = (const char*)B;

    f32x4 acc[4][4];
    #pragma unroll
    for (int i = 0; i < 4; i++)
        #pragma unroll
        for (int j = 0; j < 4; j++) acc[i][j] = (f32x4){0.f, 0.f, 0.f, 0.f};

    const int wm = wave >> 1, wn = wave & 1;
    const int fr = lane & 15, kg = lane >> 4;

    for (int k0 = 0; k0 < NE; k0 += 64) {
        #pragma unroll
        for (int j = 0; j < 4; j++) {
            gload16(pA + aoff[j], &smem[0][wave * 32 + j * 8][0]);
            gload16(pB + boff[j], &smem[1][wave * 32 + j * 8][0]);
            aoff[j] += 128; boff[j] += 128;
        }
        __syncthreads();

        #pragma unroll
        for (int kh = 0; kh < 2; kh++) {
            bf16x8 af[4], bf[4];
            #pragma unroll
            for (int f = 0; f < 4; f++) {
                int ra = wm * 64 + f * 16 + fr;
                int ca = ((kh * 4 + kg) ^ (ra & 7)) << 4;
                af[f] = *(const bf16x8*)((const char*)&smem[0][0][0] + ra * 128 + ca);
                int rb = wn * 64 + f * 16 + fr;
                int cb = ((kh * 4 + kg) ^ (rb & 7)) << 4;
                bf[f] = *(const bf16x8*)((const char*)&smem[1][0][0] + rb * 128 + cb);
            }
            #pragma unroll
            for (int fm = 0; fm < 4; fm++)
                #pragma unroll
                for (int fn = 0; fn < 4; fn++)
                    acc[fm][fn] = __builtin_amdgcn_mfma_f32_16x16x32_bf16(
                        af[fm], bf[fn], acc[fm][fn], 0, 0, 0);
        }
        __syncthreads();
    }

    #pragma unroll
    for (int fm = 0; fm < 4; fm++)
        #pragma unroll
        for (int fn = 0; fn < 4; fn++) {
            int col = wn * 64 + fn * 16 + fr;
            int row = wm * 64 + fm * 16 + kg * 4;
            const int seg = n0 >> 7;              // tile-uniform: 0=q 1=k 2=v
            unsigned short* dst = (seg == 0) ? o0 : ((seg == 1) ? o1 : o2);
            const float mult = (seg == 0) ? QSCALE : 1.f;
            float bv = bias[z * NKV + n0 + col];
            #pragma unroll
            for (int r = 0; r < 4; r++)
                dst[((size_t)(z * SEQ + s0 + row + r)) * DIM + col] =
                    f32_to_bf16_rn((acc[fm][fn][r] + bv) * mult);
        }
}

// ============ out-projection GEMM, 64x128 tile, 128 thr / 2 waves ============
__global__ __launch_bounds__(128, 3) void gemm_out_kernel(
    const unsigned short* __restrict__ A, const unsigned short* __restrict__ B,
    const float* __restrict__ bias, float* __restrict__ out)
{
    __shared__ unsigned short As[64][64];    // [m][k] 8 KiB
    __shared__ unsigned short Bs[128][64];   // [n][k] 16 KiB
    const int tid = threadIdx.x;
    const int wave = tid >> 6, lane = tid & 63;
    const int s0 = blockIdx.x * 64, n0 = blockIdx.y * 128;

    const int srow = lane >> 3;
    const int sswz = ((lane & 7) ^ srow) << 4;
    size_t aof[4], boff[4], boff2[4];
    #pragma unroll
    for (int j = 0; j < 4; j++) {
        int ra = s0 + wave * 32 + j * 8 + srow;
        aof[j] = 2 * ((size_t)ra * NE) + sswz;
        int rb = n0 + wave * 64 + j * 8 + srow;
        boff[j] = 2 * ((size_t)rb * NE) + sswz;
        int rb2 = n0 + wave * 64 + 32 + j * 8 + srow;
        boff2[j] = 2 * ((size_t)rb2 * NE) + sswz;
    }
    const char* pA = (const char*)A;
    const char* pB = (const char*)B;

    f32x4 acc[4][4];
    #pragma unroll
    for (int i = 0; i < 4; i++)
        #pragma unroll
        for (int j = 0; j < 4; j++) acc[i][j] = (f32x4){0.f, 0.f, 0.f, 0.f};

    const int fr = lane & 15, kg = lane >> 4;

    for (int k0 = 0; k0 < NE; k0 += 64) {
        #pragma unroll
        for (int j = 0; j < 4; j++) {
            gload16(pA + aof[j], &As[wave * 32 + j * 8][0]);
            gload16(pB + boff[j], &Bs[wave * 64 + j * 8][0]);
            gload16(pB + boff2[j], &Bs[wave * 64 + 32 + j * 8][0]);
            aof[j] += 128; boff[j] += 128; boff2[j] += 128;
        }
        __syncthreads();

        #pragma unroll
        for (int kh = 0; kh < 2; kh++) {
            bf16x8 af[4], bf[4];
            #pragma unroll
            for (int f = 0; f < 4; f++) {
                int ra = f * 16 + fr;                       // all M rows (0..63)
                int ca = ((kh * 4 + kg) ^ (ra & 7)) << 4;
                af[f] = *(const bf16x8*)((const char*)&As[0][0] + ra * 128 + ca);
                int rb = wave * 64 + f * 16 + fr;           // this wave's N-half
                int cb = ((kh * 4 + kg) ^ (rb & 7)) << 4;
                bf[f] = *(const bf16x8*)((const char*)&Bs[0][0] + rb * 128 + cb);
            }
            #pragma unroll
            for (int fm = 0; fm < 4; fm++)
                #pragma unroll
                for (int fn = 0; fn < 4; fn++)
                    acc[fm][fn] = __builtin_amdgcn_mfma_f32_16x16x32_bf16(
                        af[fm], bf[fn], acc[fm][fn], 0, 0, 0);
        }
        __syncthreads();
    }

    #pragma unroll
    for (int fm = 0; fm < 4; fm++)
        #pragma unroll
        for (int fn = 0; fn < 4; fn++) {
            int col = n0 + wave * 64 + fn * 16 + fr;
            int row = s0 + fm * 16 + kg * 4;
            float bv = bias[col];
            #pragma unroll
            for (int r = 0; r < 4; r++)
                out[(size_t)(row + r) * NE + col] = acc[fm][fn][r] + bv;
        }
}

// ============ attention partial: split-KV, QBLK=128, 4 waves ============
// 24 units/head: u<8 -> chunk0 of qb=8+u (16 tiles, slot 0);
// u>=8 pairs p=(u-8)>>1: even -> DIRECT qb=7-p (16-2p tiles, writes AOb);
// odd -> chunk1 of qb=15-p (16-2p tiles, slot 1). Lengths descend -> LPT.
// 4 waves share one K (16 KB) + Vt (18 KB) stage -> staging/barriers per
// FLOP halve vs QBLK=64; LDS 34 KB -> 4 blocks/CU x 4 waves = 16 waves/CU.
// Per-wave math identical to R9/R11 (32 q-rows each, Q0 = qb*128 + w*32).
__global__ __launch_bounds__(256, 3) void attn_partial_kernel(
    const unsigned short* __restrict__ Qb, const unsigned short* __restrict__ Kb,
    const unsigned short* __restrict__ Vb, char* __restrict__ partB,
    unsigned short* __restrict__ AOb)
{
    const int uid = (int)blockIdx.x;
    const int h = uid & 15;
    const int u = uid >> 4;                  // 0..23, ascending = long first
    int qb, t_begin, t_end, chunk;
    bool direct;
    if (u < 8) {
        qb = 8 + u; t_begin = 0; t_end = 16; chunk = 0; direct = false;
    } else {
        int p = (u - 8) >> 1;
        if (((u - 8) & 1) == 0) { qb = 7 - p;  t_begin = 0;  t_end = 2 * qb + 2; chunk = 0; direct = true; }
        else                    { qb = 15 - p; t_begin = 16; t_end = 2 * qb + 2; chunk = 1; direct = false; }
    }
    const int sidx = direct ? 0 : ((h * 8 + (qb - 8)) * 2 + chunk);
    char* slotB = partB + (size_t)sidx * PSLOT_B;

    const char* kh = (const char*)(Kb + (size_t)h * SEQ * DIM);
    const unsigned short* vh = Vb + (size_t)h * SEQ * DIM;

    __shared__ __align__(16) unsigned short Klds[64 * 128];   // 16 KB, single buffer
    __shared__ __align__(16) unsigned short Vt[128][72];      // V^T [d][key], 18 KB

    const int tid = threadIdx.x;
    const int w = tid >> 6, lane = tid & 63;
    const int cc = lane & 31, hh = lane >> 5;
    const int Q0 = qb * 128 + w * 32;        // lane's q = Q0 + cc

    bf16x8 qf[8];
    {
        const unsigned short* qrow = Qb + ((size_t)h * SEQ + Q0 + cc) * DIM;
        #pragma unroll
        for (int st = 0; st < 8; st++)
            qf[st] = *(const bf16x8*)&qrow[st * 16 + hh * 8];
    }

    const int key0 = (tid & 31) * 2;         // V staging: 2 keys x 16 dims/thread
    const int dbase = (tid >> 5) * 16;       // 8 dim-groups x 16

    f32x16 oacc[4];
    #pragma unroll
    for (int dt = 0; dt < 4; dt++)
        #pragma unroll
        for (int r = 0; r < 16; r++) oacc[dt][r] = 0.f;
    float m_run = -FLT_MAX, l_run = 0.f;

    u16x8 vrA[2], vrB[2];                    // V prefetch regs (16 dims x 2 keys)

    // ---- prologue: stage tile t_begin (K -> Klds, V -> regs -> Vt) ----
    {
        const int tb0 = t_begin * 64;
        #pragma unroll
        for (int j = 0; j < 4; j++) {
            int row = w * 16 + j * 4 + (lane >> 4);
            gload16(kh + (size_t)(tb0 + row) * 256 + (((lane & 15) ^ (row & 7)) << 4),
                    &Klds[(w * 16 + j * 4) * 128]);
        }
        const u16x8* p0 = (const u16x8*)&vh[(size_t)(tb0 + key0) * DIM + dbase];
        const u16x8* p1 = (const u16x8*)&vh[(size_t)(tb0 + key0 + 1) * DIM + dbase];
        vrA[0] = p0[0]; vrA[1] = p0[1]; vrB[0] = p1[0]; vrB[1] = p1[1];
        #pragma unroll
        for (int g = 0; g < 2; g++)
            #pragma unroll
            for (int j = 0; j < 8; j++)
                *(unsigned*)&Vt[dbase + g * 8 + j][key0] =
                    (unsigned)(unsigned short)vrA[g][j] |
                    ((unsigned)(unsigned short)vrB[g][j] << 16);
        asm volatile("s_waitcnt vmcnt(0)" ::: "memory");
        __syncthreads();
    }

    for (int t = t_begin; t < t_end; t++) {
        const int t0 = t * 64;
        const bool notlast = (t + 1 < t_end);
        const int t1 = t0 + 64;

        // ---- V(t+1) prefetch into regs (issued early, consumed at commit) ----
        if (notlast) {
            const u16x8* p0 = (const u16x8*)&vh[(size_t)(t1 + key0) * DIM + dbase];
            const u16x8* p1 = (const u16x8*)&vh[(size_t)(t1 + key0 + 1) * DIM + dbase];
            vrA[0] = p0[0]; vrA[1] = p0[1]; vrB[0] = p1[0]; vrB[1] = p1[1];
        }

        // ---- QK^T (swapped): S^T from Klds (G21 swizzle) ----
        f32x16 s0, s1;
        #pragma unroll
        for (int r = 0; r < 16; r++) { s0[r] = 0.f; s1[r] = 0.f; }
        __builtin_amdgcn_s_setprio(1);
        #pragma unroll
        for (int st = 0; st < 8; st++) {
            int r0 = cc, r1 = 32 + cc;
            bf16x8 kf0 = *(const bf16x8*)((const char*)&Klds[0] +
                            r0 * 256 + (((2 * st + hh) ^ (r0 & 7)) << 4));
            bf16x8 kf1 = *(const bf16x8*)((const char*)&Klds[0] +
                            r1 * 256 + (((2 * st + hh) ^ (r1 & 7)) << 4));
            s0 = __builtin_amdgcn_mfma_f32_32x32x16_bf16(kf0, qf[st], s0, 0, 0, 0);
            s1 = __builtin_amdgcn_mfma_f32_32x32x16_bf16(kf1, qf[st], s1, 0, 0, 0);
        }
        __builtin_amdgcn_s_setprio(0);

        // ---- causal mask (wave-uniform: any key in tile can exceed Q0) ----
        if (t0 + 63 > Q0) {
            const int q = Q0 + cc;
            #pragma unroll
            for (int r = 0; r < 16; r++) {
                int krow = (r & 3) + 8 * (r >> 2) + 4 * hh;
                s0[r] = (t0 + krow > q) ? -3.0e38f : s0[r];
                s1[r] = (t0 + 32 + krow > q) ? -3.0e38f : s1[r];
            }
        }

        // ---- online softmax; T13 defer-max ----
        float t4[4];
        #pragma unroll
        for (int j = 0; j < 4; j++) t4[j] = fmaxf(s0[j], s1[j]);
        #pragma unroll
        for (int r = 4; r < 16; r++) t4[r & 3] = fmaxf(t4[r & 3], fmaxf(s0[r], s1[r]));
        float mx = fmaxf(fmaxf(t4[0], t4[1]), fmaxf(t4[2], t4[3]));
        mx = fmaxf(mx, __shfl_xor(mx, 32));
        const bool nog = __all((int)(mx - m_run <= 8.f));   // wave-uniform
        float sc = 1.f;
        if (!nog) {
            float m_new = fmaxf(m_run, mx);
            sc = __expf(m_run - m_new);
            m_run = m_new;
        }

        float e4[4] = {0.f, 0.f, 0.f, 0.f};
        #pragma unroll
        for (int r = 0; r < 16; r++) {
            s0[r] = __expf(s0[r] - m_run);
            s1[r] = __expf(s1[r] - m_run);
            e4[r & 3] += s0[r] + s1[r];
        }
        float psum = (e4[0] + e4[1]) + (e4[2] + e4[3]);
        psum += __shfl_xor(psum, 32);
        l_run = l_run * sc + psum;
        if (!nog) {
            #pragma unroll
            for (int dt = 0; dt < 4; dt++)
                #pragma unroll
                for (int r = 0; r < 16; r++) oacc[dt][r] *= sc;
        }

        // ---- pack P to bf16 dwords ----
        unsigned pd[16];
        #pragma unroll
        for (int uu = 0; uu < 8; uu++) {
            pd[uu]     = cvt_pk_bf16(s0[2 * uu], s0[2 * uu + 1]);
            pd[8 + uu] = cvt_pk_bf16(s1[2 * uu], s1[2 * uu + 1]);
        }

        // ---- PV: O^T += V^T . P^T ----
        __builtin_amdgcn_s_setprio(1);
        #pragma unroll
        for (int km = 0; km < 4; km++) {
            u32x2 sA = __builtin_amdgcn_permlane32_swap(pd[4 * km + 0], pd[4 * km + 2], false, false);
            u32x2 sB = __builtin_amdgcn_permlane32_swap(pd[4 * km + 1], pd[4 * km + 3], false, false);
            u32x4 pw; pw[0] = sA[0]; pw[1] = sB[0]; pw[2] = sA[1]; pw[3] = sB[1];
            bf16x8 pb = __builtin_bit_cast(bf16x8, pw);
            #pragma unroll
            for (int dt = 0; dt < 4; dt++) {
                bf16x8 vf = *(const bf16x8*)&Vt[dt * 32 + cc][km * 16 + hh * 8];
                oacc[dt] = __builtin_amdgcn_mfma_f32_32x32x16_bf16(vf, pb, oacc[dt], 0, 0, 0);
            }
        }
        __builtin_amdgcn_s_setprio(0);

        // ---- commit window: K(t+1) gloads + Vt(t+1) writes between barriers ----
        if (notlast) {
            __syncthreads();                 // all QK reads of Klds + PV reads of Vt done
            #pragma unroll
            for (int j = 0; j < 4; j++) {
                int row = w * 16 + j * 4 + (lane >> 4);
                gload16(kh + (size_t)(t1 + row) * 256 + (((lane & 15) ^ (row & 7)) << 4),
                        &Klds[(w * 16 + j * 4) * 128]);
            }
            #pragma unroll
            for (int g = 0; g < 2; g++)
                #pragma unroll
                for (int j = 0; j < 8; j++)
                    *(unsigned*)&Vt[dbase + g * 8 + j][key0] =
                        (unsigned)(unsigned short)vrA[g][j] |
                        ((unsigned)(unsigned short)vrB[g][j] << 16);
            asm volatile("s_waitcnt vmcnt(0)" ::: "memory");
            __syncthreads();                 // Klds(t+1) + Vt(t+1) visible
        }
    }

    // ---- epilogue ----
    const int prow = w * 32 + cc;            // 0..127
    const float inv = 1.f / l_run;
    if (direct) {
        unsigned short* aorow = AOb + (size_t)(Q0 + cc) * NE + h * DIM;
        #pragma unroll
        for (int dt = 0; dt < 4; dt++)
            #pragma unroll
            for (int m = 0; m < 4; m++) {
                unsigned lo = cvt_pk_bf16(oacc[dt][4 * m + 0] * inv, oacc[dt][4 * m + 1] * inv);
                unsigned hi = cvt_pk_bf16(oacc[dt][4 * m + 2] * inv, oacc[dt][4 * m + 3] * inv);
                u32x2 pk; pk[0] = lo; pk[1] = hi;
                *(u32x2*)&aorow[dt * 32 + 8 * m + 4 * hh] = pk;
            }
    } else {
        float* mf = (float*)slotB;
        float* lf = mf + 128;
        if (hh == 0) { mf[prow] = m_run; lf[prow] = l_run; }
        unsigned short* orow = (unsigned short*)(slotB + 1024) + (size_t)prow * 128;
        #pragma unroll
        for (int dt = 0; dt < 4; dt++)
            #pragma unroll
            for (int m = 0; m < 4; m++) {
                unsigned lo = cvt_pk_bf16(oacc[dt][4 * m + 0] * inv, oacc[dt][4 * m + 1] * inv);
                unsigned hi = cvt_pk_bf16(oacc[dt][4 * m + 2] * inv, oacc[dt][4 * m + 3] * inv);
                u32x2 pk; pk[0] = lo; pk[1] = hi;
                *(u32x2*)&orow[dt * 32 + 8 * m + 4 * hh] = pk;
            }
    }
}

// ============ merge 2 partials -> AO bf16 (qb >= 8 only) ============
__global__ __launch_bounds__(128) void attn_merge_kernel(
    const char* __restrict__ partB, unsigned short* __restrict__ AOb)
{
    const int blk = (int)blockIdx.x;       // 128
    const int h = blk >> 3, qbm = blk & 7; // qb = 8 + qbm
    const char* s0B = partB + (size_t)((h * 8 + qbm) * 2) * PSLOT_B;
    const char* s1B = s0B + PSLOT_B;
    const float* m0 = (const float*)s0B; const float* l0 = m0 + 128;
    const float* m1 = (const float*)s1B; const float* l1 = m1 + 128;
    const unsigned short* O0 = (const unsigned short*)(s0B + 1024);
    const unsigned short* O1 = (const unsigned short*)(s1B + 1024);

    const int tid = threadIdx.x;
    const int f4 = tid & 31;               // dim quad
    const int rg = tid >> 5;               // row group 0..3

    #pragma unroll 1
    for (int j = 0; j < 32; j++) {
        const int row = rg + 4 * j;
        float M = fmaxf(m0[row], m1[row]);
        float w0 = __expf(m0[row] - M) * l0[row];
        float w1 = __expf(m1[row] - M) * l1[row];
        float inv = 1.f / (w0 + w1);
        w0 *= inv; w1 *= inv;
        u32x2 a = *(const u32x2*)&O0[(size_t)row * 128 + f4 * 4];
        u32x2 b = *(const u32x2*)&O1[(size_t)row * 128 + f4 * 4];
        float r0 = w0 * bf16lo(a[0]) + w1 * bf16lo(b[0]);
        float r1 = w0 * bf16hi(a[0]) + w1 * bf16hi(b[0]);
        float r2 = w0 * bf16lo(a[1]) + w1 * bf16lo(b[1]);
        float r3 = w0 * bf16hi(a[1]) + w1 * bf16hi(b[1]);
        u32x2 pk; pk[0] = cvt_pk_bf16(r0, r1); pk[1] = cvt_pk_bf16(r2, r3);
        *(u32x2*)&AOb[(size_t)((8 + qbm) * 128 + row) * NE + h * DIM + f4 * 4] = pk;
    }
}

extern "C" void kernel_launch(void* const* d_in, const int* in_sizes, int n_in,
                              void* d_out, int out_size, void* d_ws, size_t ws_size,
                              hipStream_t stream) {
    const float* H    = (const float*)d_in[0];   // [2048][2048]
    const float* Wqkv = (const float*)d_in[1];   // [16][2048][384]
    const float* bqkv = (const float*)d_in[2];   // [16][384]
    const float* Wout = (const float*)d_in[3];   // [2048][2048]
    const float* bout = (const float*)d_in[4];   // [2048]
    float* out = (float*)d_out;

    // ws layout, all inside the PROVEN <=96 MiB envelope (max touched: 81 MiB).
    char* W8 = (char*)d_ws;
    const size_t MiB = 1ull << 20;
    unsigned short* qb  = (unsigned short*)(W8 + 0);         // [16][2048][128] bf16 (pre-scaled)
    unsigned short* kb  = (unsigned short*)(W8 + 8 * MiB);
    unsigned short* vb  = (unsigned short*)(W8 + 16 * MiB);
    unsigned short* Wob = (unsigned short*)(W8 + 24 * MiB);  // [2048][2048] (n-major)
    unsigned short* AOb = (unsigned short*)(W8 + 32 * MiB);  // [2048][2048]
    char* part          = (char*)(W8 + 40 * MiB);            // 256 x 33792 B = 8.25 MiB
    unsigned short* Hb  = (unsigned short*)(W8 + 49 * MiB);  // [2048][2048]
    unsigned short* Wqb = (unsigned short*)(W8 + 57 * MiB);  // [16][384][2048] -> ends 81 MiB

    convert_bf16_kernel<<<1024, 256, 0, stream>>>(H, Hb, SEQ * NE / 4);
    transpose_bf16_kernel<<<dim3(NE / 64, NKV / 64, NH), 256, 0, stream>>>(
        Wqkv, Wqb, NE, NKV);
    transpose_bf16_kernel<<<dim3(NE / 64, NE / 64, 1), 256, 0, stream>>>(
        Wout, Wob, NE, NE);
    gemm_qkv_kernel<<<dim3(SEQ / 128, NKV / 128, NH), 256, 0, stream>>>(
        Hb, Wqb, bqkv, qb, kb, vb);
    attn_partial_kernel<<<dim3(NUNITS), 256, 0, stream>>>(qb, kb, vb, part, AOb);
    attn_merge_kernel<<<dim3(128), 128, 0, stream>>>(part, AOb);
    gemm_out_kernel<<<dim3(SEQ / 64, NE / 128), 128, 0, stream>>>(
        AOb, Wob, bout, out);
}

// Round 13
// 159.306 us; speedup vs baseline: 1.1984x; 1.1984x over previous
//
#include <hip/hip_runtime.h>
#include <cfloat>

#define SEQ   2048
#define NE    2048
#define NH    16
#define DIM   128
#define NKV   384
#define QSCALE 0.022097086912079611f  // 1/sqrt(2048)

typedef __attribute__((ext_vector_type(8))) short bf16x8;      // MFMA A/B frag (4 VGPR)
typedef __attribute__((ext_vector_type(4))) float f32x4;       // 16x16 C/D frag
typedef __attribute__((ext_vector_type(16))) float f32x16;     // 32x32 C/D frag
typedef __attribute__((ext_vector_type(8))) unsigned short u16x8;
typedef __attribute__((ext_vector_type(4))) unsigned int u32x4;
typedef __attribute__((ext_vector_type(2))) unsigned int u32x2;

#define PSLOT_B 16896u       // bytes per slot: f32 m[64], l[64], bf16 O[64][128]
#define NUNITS  768          // 16 heads x 48 units (chunk = 16 KV-tiles)

__device__ __forceinline__ unsigned short f32_to_bf16_rn(float x) {
    unsigned u = __builtin_bit_cast(unsigned, x);
    u += 0x7fffu + ((u >> 16) & 1u);          // round-to-nearest-even
    return (unsigned short)(u >> 16);
}

__device__ __forceinline__ unsigned cvt_pk_bf16(float lo, float hi) {
    unsigned r;
    asm("v_cvt_pk_bf16_f32 %0, %1, %2" : "=v"(r) : "v"(lo), "v"(hi));
    return r;
}
__device__ __forceinline__ float bf16lo(unsigned w) {
    return __builtin_bit_cast(float, w << 16);
}
__device__ __forceinline__ float bf16hi(unsigned w) {
    return __builtin_bit_cast(float, w & 0xFFFF0000u);
}

__device__ __forceinline__ void gload16(const void* g, void* l) {
    __builtin_amdgcn_global_load_lds(
        (const __attribute__((address_space(1))) unsigned int*)g,
        (__attribute__((address_space(3))) unsigned int*)l, 16, 0, 0);
}

// ============ fused prep: convert H + transpose Wqkv + transpose Wout ============
// blocks 0..1023: H fp32 -> bf16 (grid-stride).
// blocks 1024..4095: Wqkv [16][2048][384] -> Wqb [16][384][2048].
// blocks 4096..5119: Wout [2048][2048] -> Wob [2048][2048] (n-major).
__device__ __forceinline__ void transpose_tile_64(
    const float* __restrict__ src, unsigned short* __restrict__ dst,
    int K, int N, int kt, int nt, float (*tile)[65], int tid)
{
    #pragma unroll
    for (int i = 0; i < 4; i++) {
        int idx = tid + 256 * i;                 // 64 rows x 16 float4
        int kk = idx >> 4, n4 = idx & 15;
        float4 val = *(const float4*)&src[(size_t)(kt * 64 + kk) * N + nt * 64 + n4 * 4];
        tile[kk][n4 * 4 + 0] = val.x; tile[kk][n4 * 4 + 1] = val.y;
        tile[kk][n4 * 4 + 2] = val.z; tile[kk][n4 * 4 + 3] = val.w;
    }
    __syncthreads();
    #pragma unroll
    for (int i = 0; i < 2; i++) {
        int idx = tid + 256 * i;                 // 64 rows x 8 chunks
        int nn = idx >> 3, k8 = idx & 7;
        u16x8 hv;
        #pragma unroll
        for (int j = 0; j < 8; j++)
            hv[j] = f32_to_bf16_rn(tile[k8 * 8 + j][nn]);
        size_t off = (size_t)(nt * 64 + nn) * K + kt * 64 + k8 * 8;
        *(u16x8*)&dst[off] = hv;
    }
}

__global__ __launch_bounds__(256) void prep_kernel(
    const float* __restrict__ H, const float* __restrict__ Wqkv,
    const float* __restrict__ Wout,
    unsigned short* __restrict__ Hb, unsigned short* __restrict__ Wqb,
    unsigned short* __restrict__ Wob)
{
    __shared__ float tile[64][65];
    const int b = (int)blockIdx.x;
    const int tid = threadIdx.x;
    if (b < 1024) {
        const int n4 = SEQ * NE / 4;
        for (int i = b * 256 + tid; i < n4; i += 1024 * 256) {
            float4 x = ((const float4*)H)[i];
            ushort4 h;
            h.x = f32_to_bf16_rn(x.x);
            h.y = f32_to_bf16_rn(x.y);
            h.z = f32_to_bf16_rn(x.z);
            h.w = f32_to_bf16_rn(x.w);
            ((ushort4*)Hb)[i] = h;
        }
    } else if (b < 4096) {
        const int idx = b - 1024;                // 32 x 6 x 16
        const int kt = idx & 31;
        const int nt = (idx >> 5) % 6;
        const int hh = (idx >> 5) / 6;
        transpose_tile_64(Wqkv + (size_t)hh * NE * NKV,
                          Wqb + (size_t)hh * NKV * NE,
                          NE, NKV, kt, nt, tile, tid);
    } else {
        const int idx = b - 4096;                // 32 x 32
        const int kt = idx & 31;
        const int nt = idx >> 5;
        transpose_tile_64(Wout, Wob, NE, NE, kt, nt, tile, tid);
    }
}

// ============ bf16 MFMA GEMM, 128x128 (qkv projection) ============
// seg 0 -> q [h][s][d] (pre-scaled); seg 1 -> k [h][s][d];
// seg 2 -> V TRANSPOSED [h][d][s] (packed 8B stores, s-contiguous) so attn
// can stage V^T rows via global_load_lds exactly like K.
__global__ __launch_bounds__(256, 4) void gemm_qkv_kernel(
    const unsigned short* __restrict__ A, const unsigned short* __restrict__ B,
    const float* __restrict__ bias,
    unsigned short* __restrict__ o0, unsigned short* __restrict__ o1,
    unsigned short* __restrict__ o2)
{
    __shared__ unsigned short smem[2][128][64];
    const int tid = threadIdx.x;
    const int wave = tid >> 6, lane = tid & 63;
    const int s0 = blockIdx.x * 128, n0 = blockIdx.y * 128, z = blockIdx.z;
    const int bRowBase = z * NKV + n0;

    const int srow = lane >> 3;
    const int sswz = ((lane & 7) ^ srow) << 4;
    size_t aoff[4], boff[4];
    #pragma unroll
    for (int j = 0; j < 4; j++) {
        int ra = s0 + wave * 32 + j * 8 + srow;
        int rb = bRowBase + wave * 32 + j * 8 + srow;
        aoff[j] = 2 * ((size_t)ra * NE) + sswz;
        boff[j] = 2 * ((size_t)rb * NE) + sswz;
    }
    const char* pA = (const char*)A;
    const char* pB = (const char*)B;

    f32x4 acc[4][4];
    #pragma unroll
    for (int i = 0; i < 4; i++)
        #pragma unroll
        for (int j = 0; j < 4; j++) acc[i][j] = (f32x4){0.f, 0.f, 0.f, 0.f};

    const int wm = wave >> 1, wn = wave & 1;
    const int fr = lane & 15, kg = lane >> 4;

    for (int k0 = 0; k0 < NE; k0 += 64) {
        #pragma unroll
        for (int j = 0; j < 4; j++) {
            gload16(pA + aoff[j], &smem[0][wave * 32 + j * 8][0]);
            gload16(pB + boff[j], &smem[1][wave * 32 + j * 8][0]);
            aoff[j] += 128; boff[j] += 128;
        }
        __syncthreads();

        #pragma unroll
        for (int kh = 0; kh < 2; kh++) {
            bf16x8 af[4], bf[4];
            #pragma unroll
            for (int f = 0; f < 4; f++) {
                int ra = wm * 64 + f * 16 + fr;
                int ca = ((kh * 4 + kg) ^ (ra & 7)) << 4;
                af[f] = *(const bf16x8*)((const char*)&smem[0][0][0] + ra * 128 + ca);
                int rb = wn * 64 + f * 16 + fr;
                int cb = ((kh * 4 + kg) ^ (rb & 7)) << 4;
                bf[f] = *(const bf16x8*)((const char*)&smem[1][0][0] + rb * 128 + cb);
            }
            #pragma unroll
            for (int fm = 0; fm < 4; fm++)
                #pragma unroll
                for (int fn = 0; fn < 4; fn++)
                    acc[fm][fn] = __builtin_amdgcn_mfma_f32_16x16x32_bf16(
                        af[fm], bf[fn], acc[fm][fn], 0, 0, 0);
        }
        __syncthreads();
    }

    const int seg = n0 >> 7;                      // tile-uniform: 0=q 1=k 2=v
    #pragma unroll
    for (int fm = 0; fm < 4; fm++)
        #pragma unroll
        for (int fn = 0; fn < 4; fn++) {
            int col = wn * 64 + fn * 16 + fr;
            int row = wm * 64 + fm * 16 + kg * 4;
            float bv = bias[z * NKV + n0 + col];
            if (seg == 2) {
                // V^T: [z][col][s], 4 consecutive s -> one 8B store
                unsigned lo = cvt_pk_bf16(acc[fm][fn][0] + bv, acc[fm][fn][1] + bv);
                unsigned hi = cvt_pk_bf16(acc[fm][fn][2] + bv, acc[fm][fn][3] + bv);
                u32x2 pk; pk[0] = lo; pk[1] = hi;
                *(u32x2*)&o2[((size_t)z * DIM + col) * SEQ + s0 + row] = pk;
            } else {
                unsigned short* dst = (seg == 0) ? o0 : o1;
                const float mult = (seg == 0) ? QSCALE : 1.f;
                #pragma unroll
                for (int r = 0; r < 4; r++)
                    dst[((size_t)(z * SEQ + s0 + row + r)) * DIM + col] =
                        f32_to_bf16_rn((acc[fm][fn][r] + bv) * mult);
            }
        }
}

// ============ out-projection GEMM, 64x128 tile, 128 thr / 2 waves ============
__global__ __launch_bounds__(128, 3) void gemm_out_kernel(
    const unsigned short* __restrict__ A, const unsigned short* __restrict__ B,
    const float* __restrict__ bias, float* __restrict__ out)
{
    __shared__ unsigned short As[64][64];    // [m][k] 8 KiB
    __shared__ unsigned short Bs[128][64];   // [n][k] 16 KiB
    const int tid = threadIdx.x;
    const int wave = tid >> 6, lane = tid & 63;
    const int s0 = blockIdx.x * 64, n0 = blockIdx.y * 128;

    const int srow = lane >> 3;
    const int sswz = ((lane & 7) ^ srow) << 4;
    size_t aof[4], boff[4], boff2[4];
    #pragma unroll
    for (int j = 0; j < 4; j++) {
        int ra = s0 + wave * 32 + j * 8 + srow;
        aof[j] = 2 * ((size_t)ra * NE) + sswz;
        int rb = n0 + wave * 64 + j * 8 + srow;
        boff[j] = 2 * ((size_t)rb * NE) + sswz;
        int rb2 = n0 + wave * 64 + 32 + j * 8 + srow;
        boff2[j] = 2 * ((size_t)rb2 * NE) + sswz;
    }
    const char* pA = (const char*)A;
    const char* pB = (const char*)B;

    f32x4 acc[4][4];
    #pragma unroll
    for (int i = 0; i < 4; i++)
        #pragma unroll
        for (int j = 0; j < 4; j++) acc[i][j] = (f32x4){0.f, 0.f, 0.f, 0.f};

    const int fr = lane & 15, kg = lane >> 4;

    for (int k0 = 0; k0 < NE; k0 += 64) {
        #pragma unroll
        for (int j = 0; j < 4; j++) {
            gload16(pA + aof[j], &As[wave * 32 + j * 8][0]);
            gload16(pB + boff[j], &Bs[wave * 64 + j * 8][0]);
            gload16(pB + boff2[j], &Bs[wave * 64 + 32 + j * 8][0]);
            aof[j] += 128; boff[j] += 128; boff2[j] += 128;
        }
        __syncthreads();

        #pragma unroll
        for (int kh = 0; kh < 2; kh++) {
            bf16x8 af[4], bf[4];
            #pragma unroll
            for (int f = 0; f < 4; f++) {
                int ra = f * 16 + fr;                       // all M rows (0..63)
                int ca = ((kh * 4 + kg) ^ (ra & 7)) << 4;
                af[f] = *(const bf16x8*)((const char*)&As[0][0] + ra * 128 + ca);
                int rb = wave * 64 + f * 16 + fr;           // this wave's N-half
                int cb = ((kh * 4 + kg) ^ (rb & 7)) << 4;
                bf[f] = *(const bf16x8*)((const char*)&Bs[0][0] + rb * 128 + cb);
            }
            #pragma unroll
            for (int fm = 0; fm < 4; fm++)
                #pragma unroll
                for (int fn = 0; fn < 4; fn++)
                    acc[fm][fn] = __builtin_amdgcn_mfma_f32_16x16x32_bf16(
                        af[fm], bf[fn], acc[fm][fn], 0, 0, 0);
        }
        __syncthreads();
    }

    #pragma unroll
    for (int fm = 0; fm < 4; fm++)
        #pragma unroll
        for (int fn = 0; fn < 4; fn++) {
            int col = n0 + wave * 64 + fn * 16 + fr;
            int row = s0 + fm * 16 + kg * 4;
            float bv = bias[col];
            #pragma unroll
            for (int r = 0; r < 4; r++)
                out[(size_t)(row + r) * NE + col] = acc[fm][fn][r] + bv;
        }
}

// ============ attention partial: split-KV, chunk = 16 tiles (R11 skeleton) ============
// v7: V^T produced by qkv GEMM -> V staged via global_load_lds like K (zero
// staging VALU, no reg round-trip). LDS 32 KB (K 16 + Vt 16) -> 5 blocks/CU;
// VGPR ~100 (staging regs freed). Per-tile math identical to R9/R11.
__global__ __launch_bounds__(128, 2) void attn_partial_kernel(
    const unsigned short* __restrict__ Qb, const unsigned short* __restrict__ Kb,
    const unsigned short* __restrict__ VTb, char* __restrict__ partB,
    unsigned short* __restrict__ AOb)
{
    const int uid = (int)blockIdx.x;
    const int h = uid & 15;
    const int u = uid >> 4;                  // 0..47, ascending = big first
    int qt, t_begin, t_end, chunk;
    bool direct;
    if (u < 16) {
        qt = 16 + u; t_begin = 0; t_end = 16; chunk = 0; direct = false;
    } else {
        int p = (u - 16) >> 1;
        if (((u - 16) & 1) == 0) { qt = 15 - p; t_begin = 0; t_end = qt + 1; chunk = 0; direct = true; }
        else                     { qt = 31 - p; t_begin = 16; t_end = qt + 1; chunk = 1; direct = false; }
    }
    char* slotB = partB + (size_t)((h * 16 + (qt - 16)) * 2 + chunk) * PSLOT_B;

    const char* kh  = (const char*)(Kb + (size_t)h * SEQ * DIM);    // K  [s][d]
    const char* vth = (const char*)(VTb + (size_t)h * DIM * SEQ);   // V^T [d][s]

    __shared__ __align__(16) unsigned short Klds[64 * 128];   // 16 KB (rows 256 B)
    __shared__ __align__(16) unsigned short Vt[128 * 64];     // 16 KB (rows 128 B)

    const int tid = threadIdx.x;
    const int w = tid >> 6, lane = tid & 63;
    const int cc = lane & 31, hh = lane >> 5;
    const int Q0 = qt * 64 + w * 32;         // lane's q = Q0 + cc

    bf16x8 qf[8];
    {
        const unsigned short* qrow = Qb + ((size_t)h * SEQ + Q0 + cc) * DIM;
        #pragma unroll
        for (int st = 0; st < 8; st++)
            qf[st] = *(const bf16x8*)&qrow[st * 16 + hh * 8];
    }

    // staging lane geometry
    const int k_row4 = lane >> 4;            // K: 4 rows/gload16 (256 B rows)
    const int k_slot = lane & 15;
    const int v_row8 = lane >> 3;            // Vt: 8 rows/gload16 (128 B rows)
    const int v_slot = lane & 7;

    f32x16 oacc[4];
    #pragma unroll
    for (int dt = 0; dt < 4; dt++)
        #pragma unroll
        for (int r = 0; r < 16; r++) oacc[dt][r] = 0.f;
    float m_run = -FLT_MAX, l_run = 0.f;

    // ---- prologue: stage tile t_begin (K + V^T via gload16) ----
    {
        const int tb0 = t_begin * 64;
        #pragma unroll
        for (int j = 0; j < 8; j++) {        // K rows w*32+j*4 .. +3
            int row = w * 32 + j * 4 + k_row4;
            gload16(kh + (size_t)(tb0 + row) * 256 + ((k_slot ^ (row & 7)) << 4),
                    &Klds[(w * 32 + j * 4) * 128]);
        }
        #pragma unroll
        for (int j = 0; j < 8; j++) {        // Vt rows w*64+j*8 .. +7 (row = d)
            int row = w * 64 + j * 8 + v_row8;
            gload16(vth + (size_t)row * (SEQ * 2) + tb0 * 2 + ((v_slot ^ (row & 7)) << 4),
                    &Vt[(w * 64 + j * 8) * 64]);
        }
        asm volatile("s_waitcnt vmcnt(0)" ::: "memory");
        __syncthreads();
    }

    for (int t = t_begin; t < t_end; t++) {
        const int t0 = t * 64;
        const bool notlast = (t + 1 < t_end);
        const int t1 = t0 + 64;

        // ---- QK^T (swapped): S^T from Klds (G21 swizzle) ----
        f32x16 s0, s1;
        #pragma unroll
        for (int r = 0; r < 16; r++) { s0[r] = 0.f; s1[r] = 0.f; }
        __builtin_amdgcn_s_setprio(1);
        #pragma unroll
        for (int st = 0; st < 8; st++) {
            int r0 = cc, r1 = 32 + cc;
            bf16x8 kf0 = *(const bf16x8*)((const char*)&Klds[0] +
                            r0 * 256 + (((2 * st + hh) ^ (r0 & 7)) << 4));
            bf16x8 kf1 = *(const bf16x8*)((const char*)&Klds[0] +
                            r1 * 256 + (((2 * st + hh) ^ (r1 & 7)) << 4));
            s0 = __builtin_amdgcn_mfma_f32_32x32x16_bf16(kf0, qf[st], s0, 0, 0, 0);
            s1 = __builtin_amdgcn_mfma_f32_32x32x16_bf16(kf1, qf[st], s1, 0, 0, 0);
        }
        __builtin_amdgcn_s_setprio(0);

        // ---- causal mask (diagonal tile only) ----
        if (t == qt) {
            const int q = Q0 + cc;
            #pragma unroll
            for (int r = 0; r < 16; r++) {
                int krow = (r & 3) + 8 * (r >> 2) + 4 * hh;
                s0[r] = (t0 + krow > q) ? -3.0e38f : s0[r];
                s1[r] = (t0 + 32 + krow > q) ? -3.0e38f : s1[r];
            }
        }

        // ---- online softmax; T13 defer-max ----
        float t4[4];
        #pragma unroll
        for (int j = 0; j < 4; j++) t4[j] = fmaxf(s0[j], s1[j]);
        #pragma unroll
        for (int r = 4; r < 16; r++) t4[r & 3] = fmaxf(t4[r & 3], fmaxf(s0[r], s1[r]));
        float mx = fmaxf(fmaxf(t4[0], t4[1]), fmaxf(t4[2], t4[3]));
        mx = fmaxf(mx, __shfl_xor(mx, 32));
        const bool nog = __all((int)(mx - m_run <= 8.f));   // wave-uniform
        float sc = 1.f;
        if (!nog) {
            float m_new = fmaxf(m_run, mx);
            sc = __expf(m_run - m_new);
            m_run = m_new;
        }

        float e4[4] = {0.f, 0.f, 0.f, 0.f};
        #pragma unroll
        for (int r = 0; r < 16; r++) {
            s0[r] = __expf(s0[r] - m_run);
            s1[r] = __expf(s1[r] - m_run);
            e4[r & 3] += s0[r] + s1[r];
        }
        float psum = (e4[0] + e4[1]) + (e4[2] + e4[3]);
        psum += __shfl_xor(psum, 32);
        l_run = l_run * sc + psum;
        if (!nog) {
            #pragma unroll
            for (int dt = 0; dt < 4; dt++)
                #pragma unroll
                for (int r = 0; r < 16; r++) oacc[dt][r] *= sc;
        }

        // ---- pack P to bf16 dwords ----
        unsigned pd[16];
        #pragma unroll
        for (int uu = 0; uu < 8; uu++) {
            pd[uu]     = cvt_pk_bf16(s0[2 * uu], s0[2 * uu + 1]);
            pd[8 + uu] = cvt_pk_bf16(s1[2 * uu], s1[2 * uu + 1]);
        }

        // ---- PV: O^T += V^T . P^T ----
        __builtin_amdgcn_s_setprio(1);
        #pragma unroll
        for (int km = 0; km < 4; km++) {
            u32x2 sA = __builtin_amdgcn_permlane32_swap(pd[4 * km + 0], pd[4 * km + 2], false, false);
            u32x2 sB = __builtin_amdgcn_permlane32_swap(pd[4 * km + 1], pd[4 * km + 3], false, false);
            u32x4 pw; pw[0] = sA[0]; pw[1] = sB[0]; pw[2] = sA[1]; pw[3] = sB[1];
            bf16x8 pb = __builtin_bit_cast(bf16x8, pw);
            #pragma unroll
            for (int dt = 0; dt < 4; dt++) {
                int d = dt * 32 + cc;
                bf16x8 vf = *(const bf16x8*)((const char*)&Vt[0] +
                                d * 128 + (((km * 2 + hh) ^ (d & 7)) << 4));
                oacc[dt] = __builtin_amdgcn_mfma_f32_32x32x16_bf16(vf, pb, oacc[dt], 0, 0, 0);
            }
        }
        __builtin_amdgcn_s_setprio(0);

        // ---- commit window: K(t+1) + Vt(t+1) gloads between barriers ----
        if (notlast) {
            __syncthreads();                 // all reads of Klds/Vt done
            #pragma unroll
            for (int j = 0; j < 8; j++) {
                int row = w * 32 + j * 4 + k_row4;
                gload16(kh + (size_t)(t1 + row) * 256 + ((k_slot ^ (row & 7)) << 4),
                        &Klds[(w * 32 + j * 4) * 128]);
            }
            #pragma unroll
            for (int j = 0; j < 8; j++) {
                int row = w * 64 + j * 8 + v_row8;
                gload16(vth + (size_t)row * (SEQ * 2) + t1 * 2 + ((v_slot ^ (row & 7)) << 4),
                        &Vt[(w * 64 + j * 8) * 64]);
            }
            asm volatile("s_waitcnt vmcnt(0)" ::: "memory");
            __syncthreads();                 // Klds/Vt (t+1) visible
        }
    }

    // ---- epilogue ----
    const int prow = w * 32 + cc;
    const float inv = 1.f / l_run;
    if (direct) {
        unsigned short* aorow = AOb + (size_t)(Q0 + cc) * NE + h * DIM;
        #pragma unroll
        for (int dt = 0; dt < 4; dt++)
            #pragma unroll
            for (int m = 0; m < 4; m++) {
                unsigned lo = cvt_pk_bf16(oacc[dt][4 * m + 0] * inv, oacc[dt][4 * m + 1] * inv);
                unsigned hi = cvt_pk_bf16(oacc[dt][4 * m + 2] * inv, oacc[dt][4 * m + 3] * inv);
                u32x2 pk; pk[0] = lo; pk[1] = hi;
                *(u32x2*)&aorow[dt * 32 + 8 * m + 4 * hh] = pk;
            }
    } else {
        float* mf = (float*)slotB;
        float* lf = mf + 64;
        if (hh == 0) { mf[prow] = m_run; lf[prow] = l_run; }
        unsigned short* orow = (unsigned short*)(slotB + 512) + (size_t)prow * 128;
        #pragma unroll
        for (int dt = 0; dt < 4; dt++)
            #pragma unroll
            for (int m = 0; m < 4; m++) {
                unsigned lo = cvt_pk_bf16(oacc[dt][4 * m + 0] * inv, oacc[dt][4 * m + 1] * inv);
                unsigned hi = cvt_pk_bf16(oacc[dt][4 * m + 2] * inv, oacc[dt][4 * m + 3] * inv);
                u32x2 pk; pk[0] = lo; pk[1] = hi;
                *(u32x2*)&orow[dt * 32 + 8 * m + 4 * hh] = pk;
            }
    }
}

// ============ merge 2 partials -> AO bf16 (qt >= 16 only) ============
__global__ __launch_bounds__(128) void attn_merge_kernel(
    const char* __restrict__ partB, unsigned short* __restrict__ AOb)
{
    const int blk = (int)blockIdx.x;       // 256
    const int h = blk >> 4, qtm = blk & 15;
    const char* s0B = partB + (size_t)((h * 16 + qtm) * 2) * PSLOT_B;
    const char* s1B = s0B + PSLOT_B;
    const float* m0 = (const float*)s0B; const float* l0 = m0 + 64;
    const float* m1 = (const float*)s1B; const float* l1 = m1 + 64;
    const unsigned short* O0 = (const unsigned short*)(s0B + 512);
    const unsigned short* O1 = (const unsigned short*)(s1B + 512);

    const int tid = threadIdx.x;
    const int f4 = tid & 31;               // dim quad
    const int rg = tid >> 5;               // row group 0..3

    #pragma unroll 1
    for (int j = 0; j < 16; j++) {
        const int row = rg + 4 * j;
        float M = fmaxf(m0[row], m1[row]);
        float w0 = __expf(m0[row] - M) * l0[row];
        float w1 = __expf(m1[row] - M) * l1[row];
        float inv = 1.f / (w0 + w1);
        w0 *= inv; w1 *= inv;
        u32x2 a = *(const u32x2*)&O0[(size_t)row * 128 + f4 * 4];
        u32x2 b = *(const u32x2*)&O1[(size_t)row * 128 + f4 * 4];
        float r0 = w0 * bf16lo(a[0]) + w1 * bf16lo(b[0]);
        float r1 = w0 * bf16hi(a[0]) + w1 * bf16hi(b[0]);
        float r2 = w0 * bf16lo(a[1]) + w1 * bf16lo(b[1]);
        float r3 = w0 * bf16hi(a[1]) + w1 * bf16hi(b[1]);
        u32x2 pk; pk[0] = cvt_pk_bf16(r0, r1); pk[1] = cvt_pk_bf16(r2, r3);
        *(u32x2*)&AOb[(size_t)((16 + qtm) * 64 + row) * NE + h * DIM + f4 * 4] = pk;
    }
}

extern "C" void kernel_launch(void* const* d_in, const int* in_sizes, int n_in,
                              void* d_out, int out_size, void* d_ws, size_t ws_size,
                              hipStream_t stream) {
    const float* H    = (const float*)d_in[0];   // [2048][2048]
    const float* Wqkv = (const float*)d_in[1];   // [16][2048][384]
    const float* bqkv = (const float*)d_in[2];   // [16][384]
    const float* Wout = (const float*)d_in[3];   // [2048][2048]
    const float* bout = (const float*)d_in[4];   // [2048]
    float* out = (float*)d_out;

    // ws layout, all inside the PROVEN <=96 MiB envelope (max touched: 81 MiB).
    char* W8 = (char*)d_ws;
    const size_t MiB = 1ull << 20;
    unsigned short* qb  = (unsigned short*)(W8 + 0);         // [16][2048][128] bf16 (pre-scaled)
    unsigned short* kb  = (unsigned short*)(W8 + 8 * MiB);   // [16][2048][128]
    unsigned short* vtb = (unsigned short*)(W8 + 16 * MiB);  // [16][128][2048] V^T
    unsigned short* Wob = (unsigned short*)(W8 + 24 * MiB);  // [2048][2048] (n-major)
    unsigned short* AOb = (unsigned short*)(W8 + 32 * MiB);  // [2048][2048]
    char* part          = (char*)(W8 + 40 * MiB);            // 512 x 16896 B = 8.25 MiB
    unsigned short* Hb  = (unsigned short*)(W8 + 49 * MiB);  // [2048][2048]
    unsigned short* Wqb = (unsigned short*)(W8 + 57 * MiB);  // [16][384][2048] -> ends 81 MiB

    prep_kernel<<<dim3(5120), 256, 0, stream>>>(H, Wqkv, Wout, Hb, Wqb, Wob);
    gemm_qkv_kernel<<<dim3(SEQ / 128, NKV / 128, NH), 256, 0, stream>>>(
        Hb, Wqb, bqkv, qb, kb, vtb);
    attn_partial_kernel<<<dim3(NUNITS), 128, 0, stream>>>(qb, kb, vtb, part, AOb);
    attn_merge_kernel<<<dim3(256), 128, 0, stream>>>(part, AOb);
    gemm_out_kernel<<<dim3(SEQ / 64, NE / 128), 128, 0, stream>>>(
        AOb, Wob, bout, out);
}

// Round 14
// 153.404 us; speedup vs baseline: 1.2445x; 1.0385x over previous
//
#include <hip/hip_runtime.h>
#include <cfloat>

#define SEQ   2048
#define NE    2048
#define NH    16
#define DIM   128
#define NKV   384
#define QSCALE 0.022097086912079611f  // 1/sqrt(2048)

typedef __attribute__((ext_vector_type(8))) short bf16x8;      // MFMA A/B frag (4 VGPR)
typedef __attribute__((ext_vector_type(4))) float f32x4;       // 16x16 C/D frag
typedef __attribute__((ext_vector_type(16))) float f32x16;     // 32x32 C/D frag
typedef __attribute__((ext_vector_type(8))) unsigned short u16x8;
typedef __attribute__((ext_vector_type(4))) unsigned int u32x4;
typedef __attribute__((ext_vector_type(2))) unsigned int u32x2;

#define PSLOT_B 16896u       // bytes per slot: f32 m[64], l[64], bf16 O[64][128]
#define NUNITS  768          // 16 heads x 48 units (chunk = 16 KV-tiles)

__device__ __forceinline__ unsigned short f32_to_bf16_rn(float x) {
    unsigned u = __builtin_bit_cast(unsigned, x);
    u += 0x7fffu + ((u >> 16) & 1u);          // round-to-nearest-even
    return (unsigned short)(u >> 16);
}

__device__ __forceinline__ unsigned cvt_pk_bf16(float lo, float hi) {
    unsigned r;
    asm("v_cvt_pk_bf16_f32 %0, %1, %2" : "=v"(r) : "v"(lo), "v"(hi));
    return r;
}
__device__ __forceinline__ float bf16lo(unsigned w) {
    return __builtin_bit_cast(float, w << 16);
}
__device__ __forceinline__ float bf16hi(unsigned w) {
    return __builtin_bit_cast(float, w & 0xFFFF0000u);
}

__device__ __forceinline__ void gload16(const void* g, void* l) {
    __builtin_amdgcn_global_load_lds(
        (const __attribute__((address_space(1))) unsigned int*)g,
        (__attribute__((address_space(3))) unsigned int*)l, 16, 0, 0);
}

// ============ fused prep: convert H + transpose Wqkv + transpose Wout ============
__device__ __forceinline__ void transpose_tile_64(
    const float* __restrict__ src, unsigned short* __restrict__ dst,
    int K, int N, int kt, int nt, float (*tile)[65], int tid)
{
    #pragma unroll
    for (int i = 0; i < 4; i++) {
        int idx = tid + 256 * i;                 // 64 rows x 16 float4
        int kk = idx >> 4, n4 = idx & 15;
        float4 val = *(const float4*)&src[(size_t)(kt * 64 + kk) * N + nt * 64 + n4 * 4];
        tile[kk][n4 * 4 + 0] = val.x; tile[kk][n4 * 4 + 1] = val.y;
        tile[kk][n4 * 4 + 2] = val.z; tile[kk][n4 * 4 + 3] = val.w;
    }
    __syncthreads();
    #pragma unroll
    for (int i = 0; i < 2; i++) {
        int idx = tid + 256 * i;                 // 64 rows x 8 chunks
        int nn = idx >> 3, k8 = idx & 7;
        u16x8 hv;
        #pragma unroll
        for (int j = 0; j < 8; j++)
            hv[j] = f32_to_bf16_rn(tile[k8 * 8 + j][nn]);
        size_t off = (size_t)(nt * 64 + nn) * K + kt * 64 + k8 * 8;
        *(u16x8*)&dst[off] = hv;
    }
}

__global__ __launch_bounds__(256) void prep_kernel(
    const float* __restrict__ H, const float* __restrict__ Wqkv,
    const float* __restrict__ Wout,
    unsigned short* __restrict__ Hb, unsigned short* __restrict__ Wqb,
    unsigned short* __restrict__ Wob)
{
    __shared__ float tile[64][65];
    const int b = (int)blockIdx.x;
    const int tid = threadIdx.x;
    if (b < 1024) {
        const int n4 = SEQ * NE / 4;
        for (int i = b * 256 + tid; i < n4; i += 1024 * 256) {
            float4 x = ((const float4*)H)[i];
            ushort4 h;
            h.x = f32_to_bf16_rn(x.x);
            h.y = f32_to_bf16_rn(x.y);
            h.z = f32_to_bf16_rn(x.z);
            h.w = f32_to_bf16_rn(x.w);
            ((ushort4*)Hb)[i] = h;
        }
    } else if (b < 4096) {
        const int idx = b - 1024;                // 32 x 6 x 16
        const int kt = idx & 31;
        const int nt = (idx >> 5) % 6;
        const int hh = (idx >> 5) / 6;
        transpose_tile_64(Wqkv + (size_t)hh * NE * NKV,
                          Wqb + (size_t)hh * NKV * NE,
                          NE, NKV, kt, nt, tile, tid);
    } else {
        const int idx = b - 4096;                // 32 x 32
        const int kt = idx & 31;
        const int nt = idx >> 5;
        transpose_tile_64(Wout, Wob, NE, NE, kt, nt, tile, tid);
    }
}

// ============ bf16 MFMA GEMM, 128x128 (qkv projection) ============
// T1 XCD remap: 1-D grid 768; XCD x=b&7 owns heads {2x,2x+1} -> per-XCD L2
// working set = 2 heads' weights (3 MB) instead of all 16 (24 MB).
__global__ __launch_bounds__(256, 4) void gemm_qkv_kernel(
    const unsigned short* __restrict__ A, const unsigned short* __restrict__ B,
    const float* __restrict__ bias,
    unsigned short* __restrict__ o0, unsigned short* __restrict__ o1,
    unsigned short* __restrict__ o2)
{
    __shared__ unsigned short smem[2][128][64];
    const int tid = threadIdx.x;
    const int wave = tid >> 6, lane = tid & 63;

    const int b = (int)blockIdx.x;               // 768
    const int x = b & 7, jj = b >> 3;            // jj in [0,96)
    const int z = 2 * x + (jj & 1);
    const int rest = jj >> 1;                    // [0,48)
    const int s0 = (rest & 15) * 128;            // 16 m-tiles
    const int n0 = (rest >> 4) * 128;            // 3 n-tiles
    const int bRowBase = z * NKV + n0;

    const int srow = lane >> 3;
    const int sswz = ((lane & 7) ^ srow) << 4;
    size_t aoff[4], boff[4];
    #pragma unroll
    for (int j = 0; j < 4; j++) {
        int ra = s0 + wave * 32 + j * 8 + srow;
        int rb = bRowBase + wave * 32 + j * 8 + srow;
        aoff[j] = 2 * ((size_t)ra * NE) + sswz;
        boff[j] = 2 * ((size_t)rb * NE) + sswz;
    }
    const char* pA = (const char*)A;
    const char* pB = (const char*)B;

    f32x4 acc[4][4];
    #pragma unroll
    for (int i = 0; i < 4; i++)
        #pragma unroll
        for (int j = 0; j < 4; j++) acc[i][j] = (f32x4){0.f, 0.f, 0.f, 0.f};

    const int wm = wave >> 1, wn = wave & 1;
    const int fr = lane & 15, kg = lane >> 4;

    for (int k0 = 0; k0 < NE; k0 += 64) {
        #pragma unroll
        for (int j = 0; j < 4; j++) {
            gload16(pA + aoff[j], &smem[0][wave * 32 + j * 8][0]);
            gload16(pB + boff[j], &smem[1][wave * 32 + j * 8][0]);
            aoff[j] += 128; boff[j] += 128;
        }
        __syncthreads();

        #pragma unroll
        for (int kh = 0; kh < 2; kh++) {
            bf16x8 af[4], bf[4];
            #pragma unroll
            for (int f = 0; f < 4; f++) {
                int ra = wm * 64 + f * 16 + fr;
                int ca = ((kh * 4 + kg) ^ (ra & 7)) << 4;
                af[f] = *(const bf16x8*)((const char*)&smem[0][0][0] + ra * 128 + ca);
                int rb = wn * 64 + f * 16 + fr;
                int cb = ((kh * 4 + kg) ^ (rb & 7)) << 4;
                bf[f] = *(const bf16x8*)((const char*)&smem[1][0][0] + rb * 128 + cb);
            }
            #pragma unroll
            for (int fm = 0; fm < 4; fm++)
                #pragma unroll
                for (int fn = 0; fn < 4; fn++)
                    acc[fm][fn] = __builtin_amdgcn_mfma_f32_16x16x32_bf16(
                        af[fm], bf[fn], acc[fm][fn], 0, 0, 0);
        }
        __syncthreads();
    }

    const int seg = n0 >> 7;                      // tile-uniform: 0=q 1=k 2=v
    #pragma unroll
    for (int fm = 0; fm < 4; fm++)
        #pragma unroll
        for (int fn = 0; fn < 4; fn++) {
            int col = wn * 64 + fn * 16 + fr;
            int row = wm * 64 + fm * 16 + kg * 4;
            float bv = bias[z * NKV + n0 + col];
            if (seg == 2) {
                // V^T: [z][col][s], 4 consecutive s -> one 8B store
                unsigned lo = cvt_pk_bf16(acc[fm][fn][0] + bv, acc[fm][fn][1] + bv);
                unsigned hi = cvt_pk_bf16(acc[fm][fn][2] + bv, acc[fm][fn][3] + bv);
                u32x2 pk; pk[0] = lo; pk[1] = hi;
                *(u32x2*)&o2[((size_t)z * DIM + col) * SEQ + s0 + row] = pk;
            } else {
                unsigned short* dst = (seg == 0) ? o0 : o1;
                const float mult = (seg == 0) ? QSCALE : 1.f;
                #pragma unroll
                for (int r = 0; r < 4; r++)
                    dst[((size_t)(z * SEQ + s0 + row + r)) * DIM + col] =
                        f32_to_bf16_rn((acc[fm][fn][r] + bv) * mult);
            }
        }
}

// ============ out-projection GEMM, 64x128 tile, 128 thr / 2 waves ============
// T1 XCD remap: 1-D grid 512; XCD x owns n-panels {2x,2x+1} (1 MB B hot/XCD).
__global__ __launch_bounds__(128, 3) void gemm_out_kernel(
    const unsigned short* __restrict__ A, const unsigned short* __restrict__ B,
    const float* __restrict__ bias, float* __restrict__ out)
{
    __shared__ unsigned short As[64][64];    // [m][k] 8 KiB
    __shared__ unsigned short Bs[128][64];   // [n][k] 16 KiB
    const int tid = threadIdx.x;
    const int wave = tid >> 6, lane = tid & 63;

    const int b = (int)blockIdx.x;               // 512
    const int x = b & 7, jj = b >> 3;            // [0,64)
    const int n0 = (2 * x + (jj & 1)) * 128;     // 16 n-tiles
    const int s0 = (jj >> 1) * 64;               // 32 m-tiles

    const int srow = lane >> 3;
    const int sswz = ((lane & 7) ^ srow) << 4;
    size_t aof[4], boff[4], boff2[4];
    #pragma unroll
    for (int j = 0; j < 4; j++) {
        int ra = s0 + wave * 32 + j * 8 + srow;
        aof[j] = 2 * ((size_t)ra * NE) + sswz;
        int rb = n0 + wave * 64 + j * 8 + srow;
        boff[j] = 2 * ((size_t)rb * NE) + sswz;
        int rb2 = n0 + wave * 64 + 32 + j * 8 + srow;
        boff2[j] = 2 * ((size_t)rb2 * NE) + sswz;
    }
    const char* pA = (const char*)A;
    const char* pB = (const char*)B;

    f32x4 acc[4][4];
    #pragma unroll
    for (int i = 0; i < 4; i++)
        #pragma unroll
        for (int j = 0; j < 4; j++) acc[i][j] = (f32x4){0.f, 0.f, 0.f, 0.f};

    const int fr = lane & 15, kg = lane >> 4;

    for (int k0 = 0; k0 < NE; k0 += 64) {
        #pragma unroll
        for (int j = 0; j < 4; j++) {
            gload16(pA + aof[j], &As[wave * 32 + j * 8][0]);
            gload16(pB + boff[j], &Bs[wave * 64 + j * 8][0]);
            gload16(pB + boff2[j], &Bs[wave * 64 + 32 + j * 8][0]);
            aof[j] += 128; boff[j] += 128; boff2[j] += 128;
        }
        __syncthreads();

        #pragma unroll
        for (int kh = 0; kh < 2; kh++) {
            bf16x8 af[4], bf[4];
            #pragma unroll
            for (int f = 0; f < 4; f++) {
                int ra = f * 16 + fr;                       // all M rows (0..63)
                int ca = ((kh * 4 + kg) ^ (ra & 7)) << 4;
                af[f] = *(const bf16x8*)((const char*)&As[0][0] + ra * 128 + ca);
                int rb = wave * 64 + f * 16 + fr;           // this wave's N-half
                int cb = ((kh * 4 + kg) ^ (rb & 7)) << 4;
                bf[f] = *(const bf16x8*)((const char*)&Bs[0][0] + rb * 128 + cb);
            }
            #pragma unroll
            for (int fm = 0; fm < 4; fm++)
                #pragma unroll
                for (int fn = 0; fn < 4; fn++)
                    acc[fm][fn] = __builtin_amdgcn_mfma_f32_16x16x32_bf16(
                        af[fm], bf[fn], acc[fm][fn], 0, 0, 0);
        }
        __syncthreads();
    }

    #pragma unroll
    for (int fm = 0; fm < 4; fm++)
        #pragma unroll
        for (int fn = 0; fn < 4; fn++) {
            int col = n0 + wave * 64 + fn * 16 + fr;
            int row = s0 + fm * 16 + kg * 4;
            float bv = bias[col];
            #pragma unroll
            for (int r = 0; r < 4; r++)
                out[(size_t)(row + r) * NE + col] = acc[fm][fn][r] + bv;
        }
}

// ============ attention partial: split-KV, chunk = 16 tiles ============
// T1 XCD remap: XCD x=b&7 owns heads {2x,2x+1} -> K+V working set 2 MB/XCD
// (fully L2-resident) -> commit-window staging waits hit L2 not L3/HBM.
// LPT preserved per-XCD (u = j>>1 ascending = long units first).
__global__ __launch_bounds__(128, 2) void attn_partial_kernel(
    const unsigned short* __restrict__ Qb, const unsigned short* __restrict__ Kb,
    const unsigned short* __restrict__ VTb, char* __restrict__ partB,
    unsigned short* __restrict__ AOb)
{
    const int bid = (int)blockIdx.x;         // 768
    const int x = bid & 7, jj = bid >> 3;    // jj in [0,96)
    const int h = 2 * x + (jj & 1);
    const int u = jj >> 1;                   // 0..47, ascending = big first
    int qt, t_begin, t_end, chunk;
    bool direct;
    if (u < 16) {
        qt = 16 + u; t_begin = 0; t_end = 16; chunk = 0; direct = false;
    } else {
        int p = (u - 16) >> 1;
        if (((u - 16) & 1) == 0) { qt = 15 - p; t_begin = 0; t_end = qt + 1; chunk = 0; direct = true; }
        else                     { qt = 31 - p; t_begin = 16; t_end = qt + 1; chunk = 1; direct = false; }
    }
    char* slotB = partB + (size_t)((h * 16 + (qt - 16)) * 2 + chunk) * PSLOT_B;

    const char* kh  = (const char*)(Kb + (size_t)h * SEQ * DIM);    // K  [s][d]
    const char* vth = (const char*)(VTb + (size_t)h * DIM * SEQ);   // V^T [d][s]

    __shared__ __align__(16) unsigned short Klds[64 * 128];   // 16 KB (rows 256 B)
    __shared__ __align__(16) unsigned short Vt[128 * 64];     // 16 KB (rows 128 B)

    const int tid = threadIdx.x;
    const int w = tid >> 6, lane = tid & 63;
    const int cc = lane & 31, hh = lane >> 5;
    const int Q0 = qt * 64 + w * 32;         // lane's q = Q0 + cc

    bf16x8 qf[8];
    {
        const unsigned short* qrow = Qb + ((size_t)h * SEQ + Q0 + cc) * DIM;
        #pragma unroll
        for (int st = 0; st < 8; st++)
            qf[st] = *(const bf16x8*)&qrow[st * 16 + hh * 8];
    }

    // staging lane geometry
    const int k_row4 = lane >> 4;            // K: 4 rows/gload16 (256 B rows)
    const int k_slot = lane & 15;
    const int v_row8 = lane >> 3;            // Vt: 8 rows/gload16 (128 B rows)
    const int v_slot = lane & 7;

    f32x16 oacc[4];
    #pragma unroll
    for (int dt = 0; dt < 4; dt++)
        #pragma unroll
        for (int r = 0; r < 16; r++) oacc[dt][r] = 0.f;
    float m_run = -FLT_MAX, l_run = 0.f;

    // ---- prologue: stage tile t_begin (K + V^T via gload16) ----
    {
        const int tb0 = t_begin * 64;
        #pragma unroll
        for (int j = 0; j < 8; j++) {        // K rows w*32+j*4 .. +3
            int row = w * 32 + j * 4 + k_row4;
            gload16(kh + (size_t)(tb0 + row) * 256 + ((k_slot ^ (row & 7)) << 4),
                    &Klds[(w * 32 + j * 4) * 128]);
        }
        #pragma unroll
        for (int j = 0; j < 8; j++) {        // Vt rows w*64+j*8 .. +7 (row = d)
            int row = w * 64 + j * 8 + v_row8;
            gload16(vth + (size_t)row * (SEQ * 2) + tb0 * 2 + ((v_slot ^ (row & 7)) << 4),
                    &Vt[(w * 64 + j * 8) * 64]);
        }
        asm volatile("s_waitcnt vmcnt(0)" ::: "memory");
        __syncthreads();
    }

    for (int t = t_begin; t < t_end; t++) {
        const int t0 = t * 64;
        const bool notlast = (t + 1 < t_end);
        const int t1 = t0 + 64;

        // ---- QK^T (swapped): S^T from Klds (G21 swizzle) ----
        f32x16 s0, s1;
        #pragma unroll
        for (int r = 0; r < 16; r++) { s0[r] = 0.f; s1[r] = 0.f; }
        __builtin_amdgcn_s_setprio(1);
        #pragma unroll
        for (int st = 0; st < 8; st++) {
            int r0 = cc, r1 = 32 + cc;
            bf16x8 kf0 = *(const bf16x8*)((const char*)&Klds[0] +
                            r0 * 256 + (((2 * st + hh) ^ (r0 & 7)) << 4));
            bf16x8 kf1 = *(const bf16x8*)((const char*)&Klds[0] +
                            r1 * 256 + (((2 * st + hh) ^ (r1 & 7)) << 4));
            s0 = __builtin_amdgcn_mfma_f32_32x32x16_bf16(kf0, qf[st], s0, 0, 0, 0);
            s1 = __builtin_amdgcn_mfma_f32_32x32x16_bf16(kf1, qf[st], s1, 0, 0, 0);
        }
        __builtin_amdgcn_s_setprio(0);

        // ---- causal mask (diagonal tile only) ----
        if (t == qt) {
            const int q = Q0 + cc;
            #pragma unroll
            for (int r = 0; r < 16; r++) {
                int krow = (r & 3) + 8 * (r >> 2) + 4 * hh;
                s0[r] = (t0 + krow > q) ? -3.0e38f : s0[r];
                s1[r] = (t0 + 32 + krow > q) ? -3.0e38f : s1[r];
            }
        }

        // ---- online softmax; T13 defer-max ----
        float t4[4];
        #pragma unroll
        for (int j = 0; j < 4; j++) t4[j] = fmaxf(s0[j], s1[j]);
        #pragma unroll
        for (int r = 4; r < 16; r++) t4[r & 3] = fmaxf(t4[r & 3], fmaxf(s0[r], s1[r]));
        float mx = fmaxf(fmaxf(t4[0], t4[1]), fmaxf(t4[2], t4[3]));
        mx = fmaxf(mx, __shfl_xor(mx, 32));
        const bool nog = __all((int)(mx - m_run <= 8.f));   // wave-uniform
        float sc = 1.f;
        if (!nog) {
            float m_new = fmaxf(m_run, mx);
            sc = __expf(m_run - m_new);
            m_run = m_new;
        }

        float e4[4] = {0.f, 0.f, 0.f, 0.f};
        #pragma unroll
        for (int r = 0; r < 16; r++) {
            s0[r] = __expf(s0[r] - m_run);
            s1[r] = __expf(s1[r] - m_run);
            e4[r & 3] += s0[r] + s1[r];
        }
        float psum = (e4[0] + e4[1]) + (e4[2] + e4[3]);
        psum += __shfl_xor(psum, 32);
        l_run = l_run * sc + psum;
        if (!nog) {
            #pragma unroll
            for (int dt = 0; dt < 4; dt++)
                #pragma unroll
                for (int r = 0; r < 16; r++) oacc[dt][r] *= sc;
        }

        // ---- pack P to bf16 dwords ----
        unsigned pd[16];
        #pragma unroll
        for (int uu = 0; uu < 8; uu++) {
            pd[uu]     = cvt_pk_bf16(s0[2 * uu], s0[2 * uu + 1]);
            pd[8 + uu] = cvt_pk_bf16(s1[2 * uu], s1[2 * uu + 1]);
        }

        // ---- PV: O^T += V^T . P^T ----
        __builtin_amdgcn_s_setprio(1);
        #pragma unroll
        for (int km = 0; km < 4; km++) {
            u32x2 sA = __builtin_amdgcn_permlane32_swap(pd[4 * km + 0], pd[4 * km + 2], false, false);
            u32x2 sB = __builtin_amdgcn_permlane32_swap(pd[4 * km + 1], pd[4 * km + 3], false, false);
            u32x4 pw; pw[0] = sA[0]; pw[1] = sB[0]; pw[2] = sA[1]; pw[3] = sB[1];
            bf16x8 pb = __builtin_bit_cast(bf16x8, pw);
            #pragma unroll
            for (int dt = 0; dt < 4; dt++) {
                int d = dt * 32 + cc;
                bf16x8 vf = *(const bf16x8*)((const char*)&Vt[0] +
                                d * 128 + (((km * 2 + hh) ^ (d & 7)) << 4));
                oacc[dt] = __builtin_amdgcn_mfma_f32_32x32x16_bf16(vf, pb, oacc[dt], 0, 0, 0);
            }
        }
        __builtin_amdgcn_s_setprio(0);

        // ---- commit window: K(t+1) + Vt(t+1) gloads between barriers ----
        if (notlast) {
            __syncthreads();                 // all reads of Klds/Vt done
            #pragma unroll
            for (int j = 0; j < 8; j++) {
                int row = w * 32 + j * 4 + k_row4;
                gload16(kh + (size_t)(t1 + row) * 256 + ((k_slot ^ (row & 7)) << 4),
                        &Klds[(w * 32 + j * 4) * 128]);
            }
            #pragma unroll
            for (int j = 0; j < 8; j++) {
                int row = w * 64 + j * 8 + v_row8;
                gload16(vth + (size_t)row * (SEQ * 2) + t1 * 2 + ((v_slot ^ (row & 7)) << 4),
                        &Vt[(w * 64 + j * 8) * 64]);
            }
            asm volatile("s_waitcnt vmcnt(0)" ::: "memory");
            __syncthreads();                 // Klds/Vt (t+1) visible
        }
    }

    // ---- epilogue ----
    const int prow = w * 32 + cc;
    const float inv = 1.f / l_run;
    if (direct) {
        unsigned short* aorow = AOb + (size_t)(Q0 + cc) * NE + h * DIM;
        #pragma unroll
        for (int dt = 0; dt < 4; dt++)
            #pragma unroll
            for (int m = 0; m < 4; m++) {
                unsigned lo = cvt_pk_bf16(oacc[dt][4 * m + 0] * inv, oacc[dt][4 * m + 1] * inv);
                unsigned hi = cvt_pk_bf16(oacc[dt][4 * m + 2] * inv, oacc[dt][4 * m + 3] * inv);
                u32x2 pk; pk[0] = lo; pk[1] = hi;
                *(u32x2*)&aorow[dt * 32 + 8 * m + 4 * hh] = pk;
            }
    } else {
        float* mf = (float*)slotB;
        float* lf = mf + 64;
        if (hh == 0) { mf[prow] = m_run; lf[prow] = l_run; }
        unsigned short* orow = (unsigned short*)(slotB + 512) + (size_t)prow * 128;
        #pragma unroll
        for (int dt = 0; dt < 4; dt++)
            #pragma unroll
            for (int m = 0; m < 4; m++) {
                unsigned lo = cvt_pk_bf16(oacc[dt][4 * m + 0] * inv, oacc[dt][4 * m + 1] * inv);
                unsigned hi = cvt_pk_bf16(oacc[dt][4 * m + 2] * inv, oacc[dt][4 * m + 3] * inv);
                u32x2 pk; pk[0] = lo; pk[1] = hi;
                *(u32x2*)&orow[dt * 32 + 8 * m + 4 * hh] = pk;
            }
    }
}

// ============ merge 2 partials -> AO bf16 (qt >= 16 only) ============
__global__ __launch_bounds__(128) void attn_merge_kernel(
    const char* __restrict__ partB, unsigned short* __restrict__ AOb)
{
    const int blk = (int)blockIdx.x;       // 256
    const int h = blk >> 4, qtm = blk & 15;
    const char* s0B = partB + (size_t)((h * 16 + qtm) * 2) * PSLOT_B;
    const char* s1B = s0B + PSLOT_B;
    const float* m0 = (const float*)s0B; const float* l0 = m0 + 64;
    const float* m1 = (const float*)s1B; const float* l1 = m1 + 64;
    const unsigned short* O0 = (const unsigned short*)(s0B + 512);
    const unsigned short* O1 = (const unsigned short*)(s1B + 512);

    const int tid = threadIdx.x;
    const int f4 = tid & 31;               // dim quad
    const int rg = tid >> 5;               // row group 0..3

    #pragma unroll 1
    for (int j = 0; j < 16; j++) {
        const int row = rg + 4 * j;
        float M = fmaxf(m0[row], m1[row]);
        float w0 = __expf(m0[row] - M) * l0[row];
        float w1 = __expf(m1[row] - M) * l1[row];
        float inv = 1.f / (w0 + w1);
        w0 *= inv; w1 *= inv;
        u32x2 a = *(const u32x2*)&O0[(size_t)row * 128 + f4 * 4];
        u32x2 b = *(const u32x2*)&O1[(size_t)row * 128 + f4 * 4];
        float r0 = w0 * bf16lo(a[0]) + w1 * bf16lo(b[0]);
        float r1 = w0 * bf16hi(a[0]) + w1 * bf16hi(b[0]);
        float r2 = w0 * bf16lo(a[1]) + w1 * bf16lo(b[1]);
        float r3 = w0 * bf16hi(a[1]) + w1 * bf16hi(b[1]);
        u32x2 pk; pk[0] = cvt_pk_bf16(r0, r1); pk[1] = cvt_pk_bf16(r2, r3);
        *(u32x2*)&AOb[(size_t)((16 + qtm) * 64 + row) * NE + h * DIM + f4 * 4] = pk;
    }
}

extern "C" void kernel_launch(void* const* d_in, const int* in_sizes, int n_in,
                              void* d_out, int out_size, void* d_ws, size_t ws_size,
                              hipStream_t stream) {
    const float* H    = (const float*)d_in[0];   // [2048][2048]
    const float* Wqkv = (const float*)d_in[1];   // [16][2048][384]
    const float* bqkv = (const float*)d_in[2];   // [16][384]
    const float* Wout = (const float*)d_in[3];   // [2048][2048]
    const float* bout = (const float*)d_in[4];   // [2048]
    float* out = (float*)d_out;

    // ws layout, all inside the PROVEN <=96 MiB envelope (max touched: 81 MiB).
    char* W8 = (char*)d_ws;
    const size_t MiB = 1ull << 20;
    unsigned short* qb  = (unsigned short*)(W8 + 0);         // [16][2048][128] bf16 (pre-scaled)
    unsigned short* kb  = (unsigned short*)(W8 + 8 * MiB);   // [16][2048][128]
    unsigned short* vtb = (unsigned short*)(W8 + 16 * MiB);  // [16][128][2048] V^T
    unsigned short* Wob = (unsigned short*)(W8 + 24 * MiB);  // [2048][2048] (n-major)
    unsigned short* AOb = (unsigned short*)(W8 + 32 * MiB);  // [2048][2048]
    char* part          = (char*)(W8 + 40 * MiB);            // 512 x 16896 B = 8.25 MiB
    unsigned short* Hb  = (unsigned short*)(W8 + 49 * MiB);  // [2048][2048]
    unsigned short* Wqb = (unsigned short*)(W8 + 57 * MiB);  // [16][384][2048] -> ends 81 MiB

    prep_kernel<<<dim3(5120), 256, 0, stream>>>(H, Wqkv, Wout, Hb, Wqb, Wob);
    gemm_qkv_kernel<<<dim3(768), 256, 0, stream>>>(
        Hb, Wqb, bqkv, qb, kb, vtb);
    attn_partial_kernel<<<dim3(NUNITS), 128, 0, stream>>>(qb, kb, vtb, part, AOb);
    attn_merge_kernel<<<dim3(256), 128, 0, stream>>>(part, AOb);
    gemm_out_kernel<<<dim3(512), 128, 0, stream>>>(
        AOb, Wob, bout, out);
}